// Round 16
// baseline (441.229 us; speedup 1.0000x reference)
//
#include <hip/hip_runtime.h>
#include <hip/hip_bf16.h>
#include <cstdint>

// B=2, T=2048, HID=1024, H=16, DK=DV=64, K(conv)=4. fp32 in/out.
// RICH memory plan (ws >= 40MB): ws = P0..P4 (8MB bf16 planes).
//  d_out[0,8M): xb -> Kb (k-plane);  d_out[8M,16M): W4b -> Qb (q-plane)
//  P4: [0,256K) betab fp32; [256K,512K) gkk; [1M,3M) Wgb; [3M,5M) Wob
//  P0: zq -> scan o;  P1: zk -> v-plane;  P2: zv -> g-plane;  P3: a plane
// Launches (6): cvtw -> mega_gemm2(+beta) -> conv2(q, k+kk) -> conv_v
//   -> FUSED scan+g-GEMM -> gemm_bb_ln.
//
// R16: (1) kk fused into conv_k (recompute k[t-1] in-register -- bit-identical
// bf16 -- 8-lane shfl dot, write G); kk pass + 8MB k re-read eliminated.
// (2) conv_v standalone 2048 blocks. (3) gemm_bb_ln 1024 blocks = 4/CU
// (32-row tiles, acc[1][4]; per-XCD footprint 3MB < L2). Rest proven.

using bf16 = __hip_bfloat16;
typedef __bf16 bf16x8 __attribute__((ext_vector_type(8)));
typedef __bf16 bf16x4v __attribute__((ext_vector_type(4)));
typedef float f32x4 __attribute__((ext_vector_type(4)));
typedef float f32x2 __attribute__((ext_vector_type(2)));
typedef unsigned int u32x4 __attribute__((ext_vector_type(4)));
typedef unsigned int u32x2 __attribute__((ext_vector_type(2)));

__device__ __forceinline__ __bf16 cvt_bf16(float f) {
  __hip_bfloat16 h = (__hip_bfloat16)f;
  return *reinterpret_cast<__bf16*>(&h);
}
__device__ __forceinline__ void async_copy16(const void* g, void* l) {
  __builtin_amdgcn_global_load_lds((const __attribute__((address_space(1))) void*)g,
                                   (__attribute__((address_space(3))) void*)l,
                                   16, 0, 0);
}
__device__ __forceinline__ float bcf(unsigned int u) { return __builtin_bit_cast(float, u); }
template <int CTRL>
__device__ __forceinline__ float dpp_f(float x) {
  int y = __builtin_amdgcn_update_dpp(0, __builtin_bit_cast(int, x), CTRL, 0xF, 0xF, true);
  return __builtin_bit_cast(float, y);
}

// fp32 -> bf16: x (blocks 0..4095), W4 (4096..8191), Wg (8192..9215),
// Wo (9216..10239).
__global__ __launch_bounds__(256) void cvtw_kernel(
    const float* __restrict__ x, const float* __restrict__ Wq,
    const float* __restrict__ Wk, const float* __restrict__ Wv,
    const float* __restrict__ Wa, const float* __restrict__ Wg,
    const float* __restrict__ Wo, bf16* __restrict__ xb,
    bf16* __restrict__ w4b, bf16* __restrict__ wgb, bf16* __restrict__ wob)
{
  int blk = blockIdx.x;
  const float* src;
  __bf16* dst;
  size_t off;
  if (blk < 4096) {
    src = x; dst = (__bf16*)xb;
    off = (size_t)blk * 1024 + threadIdx.x * 4;
  } else if (blk < 8192) {
    int wb = blk - 4096;
    int wi = wb >> 10;
    src = (wi == 0) ? Wq : (wi == 1) ? Wk : (wi == 2) ? Wv : Wa;
    dst = (__bf16*)w4b + (size_t)wi * 1024 * 1024;
    off = (size_t)(wb & 1023) * 1024 + threadIdx.x * 4;
  } else if (blk < 9216) {
    src = Wg; dst = (__bf16*)wgb;
    off = (size_t)(blk - 8192) * 1024 + threadIdx.x * 4;
  } else {
    src = Wo; dst = (__bf16*)wob;
    off = (size_t)(blk - 9216) * 1024 + threadIdx.x * 4;
  }
  float4 f = *(const float4*)(src + off);
  bf16x4v t;
  t[0] = cvt_bf16(f.x); t[1] = cvt_bf16(f.y); t[2] = cvt_bf16(f.z); t[3] = cvt_bf16(f.w);
  *(bf16x4v*)(dst + off) = t;
}

// C = A * Bt^T. A: MxK (bf16 async-staged unless A_FP32); Bt: NxK fp32.
// MODE 2: raw->bf16; 3: sigmoid(acc+bias)->bf16; 4: raw->fp32; 5: sigmoid(acc+bias)->fp32 TRANSPOSED
template <int MODE, bool A_FP32>
__global__ __launch_bounds__(256) void gemm_bt(
    const void* __restrict__ Av, const float* __restrict__ Bt,
    const float* __restrict__ bias, float* __restrict__ Cf, bf16* __restrict__ Cb,
    int M, int N, int K)
{
  __shared__ __align__(16) __bf16 As[128 * 32];
  __shared__ __align__(16) __bf16 Bs[128 * 32];

  const int tid  = threadIdx.x;
  const int lane = tid & 63;
  const int wave = tid >> 6;
  const int tile_m = blockIdx.y * 128;
  const int tile_n = blockIdx.x * 128;
  const int wm = (wave >> 1) * 64;
  const int wn = (wave & 1) * 64;

  const int srow = lane >> 2;
  const int scol = (lane & 3) * 8;

  f32x4 acc[4][4];
#pragma unroll
  for (int i = 0; i < 4; ++i)
#pragma unroll
    for (int j = 0; j < 4; ++j) acc[i][j] = {0.f, 0.f, 0.f, 0.f};

  for (int k0 = 0; k0 < K; k0 += 32) {
    float4 b0[2], b1[2], a0[2], a1[2];
#pragma unroll
    for (int s = 0; s < 2; ++s) {
      int brow = tile_n + s * 64 + wave * 16 + srow;
      if (brow > N - 1) brow = N - 1;
      const float* bp = Bt + (size_t)brow * K + k0 + scol;
      b0[s] = *(const float4*)bp;
      b1[s] = *(const float4*)(bp + 4);
      if (A_FP32) {
        int arow = tile_m + s * 64 + wave * 16 + srow;
        const float* ap = (const float*)Av + (size_t)arow * K + k0 + scol;
        a0[s] = *(const float4*)ap;
        a1[s] = *(const float4*)(ap + 4);
      }
    }
    __syncthreads();
#pragma unroll
    for (int s = 0; s < 2; ++s) {
      if (!A_FP32) {
        int arow = tile_m + s * 64 + wave * 16 + srow;
        async_copy16((const __bf16*)Av + (size_t)arow * K + k0 + scol,
                     &As[(s * 64 + wave * 16 + srow) * 32 + scol]);
      } else {
        bf16x8 ua;
        ua[0] = cvt_bf16(a0[s].x); ua[1] = cvt_bf16(a0[s].y);
        ua[2] = cvt_bf16(a0[s].z); ua[3] = cvt_bf16(a0[s].w);
        ua[4] = cvt_bf16(a1[s].x); ua[5] = cvt_bf16(a1[s].y);
        ua[6] = cvt_bf16(a1[s].z); ua[7] = cvt_bf16(a1[s].w);
        *(bf16x8*)&As[(s * 64 + wave * 16 + srow) * 32 + scol] = ua;
      }
      bf16x8 u;
      u[0] = cvt_bf16(b0[s].x); u[1] = cvt_bf16(b0[s].y);
      u[2] = cvt_bf16(b0[s].z); u[3] = cvt_bf16(b0[s].w);
      u[4] = cvt_bf16(b1[s].x); u[5] = cvt_bf16(b1[s].y);
      u[6] = cvt_bf16(b1[s].z); u[7] = cvt_bf16(b1[s].w);
      *(bf16x8*)&Bs[(s * 64 + wave * 16 + srow) * 32 + scol] = u;
    }
    __syncthreads();

    bf16x8 af[4], bfr[4];
#pragma unroll
    for (int i = 0; i < 4; ++i)
      af[i] = *(const bf16x8*)&As[(wm + i * 16 + (lane & 15)) * 32 + (lane >> 4) * 8];
#pragma unroll
    for (int j = 0; j < 4; ++j)
      bfr[j] = *(const bf16x8*)&Bs[(wn + j * 16 + (lane & 15)) * 32 + (lane >> 4) * 8];

#pragma unroll
    for (int i = 0; i < 4; ++i)
#pragma unroll
      for (int j = 0; j < 4; ++j)
        acc[i][j] = __builtin_amdgcn_mfma_f32_16x16x32_bf16(af[i], bfr[j], acc[i][j], 0, 0, 0);
  }

#pragma unroll
  for (int i = 0; i < 4; ++i) {
#pragma unroll
    for (int j = 0; j < 4; ++j) {
#pragma unroll
      for (int r = 0; r < 4; ++r) {
        int gm = tile_m + wm + i * 16 + (lane >> 4) * 4 + r;
        int gn = tile_n + wn + j * 16 + (lane & 15);
        if (gn < N) {
          float val = acc[i][j][r];
          if (MODE == 3 || MODE == 5) {
            float bv = bias ? bias[gn] : 0.f;
            val = 1.f / (1.f + __expf(-(val + bv)));
          }
          if (MODE == 4)      Cf[(size_t)gm * N + gn] = val;
          else if (MODE == 5) Cf[(size_t)gn * M + gm] = val;
          else                Cb[(size_t)gm * N + gn] = (bf16)val;
        }
      }
    }
  }
}

// Final GEMM with fused LN+gate. 32-row tiles -> 1024 blocks = 4/CU.
// Per head: full 64-k B-slab staged (Bs2), head loop software-pipelined.
// XCD-bijective swizzle: per-XCD footprint = 2MB Wob + 1MB o/g < L2.
__global__ __launch_bounds__(256) void gemm_bb_ln(
    const bf16* __restrict__ o, const bf16* __restrict__ g,
    const float* __restrict__ lnw, const float* __restrict__ lnb,
    const bf16* __restrict__ Bw, float* __restrict__ C)
{
  __shared__ __align__(16) __bf16 As2[32][72];        // 4.5 KB (72-pad)
  __shared__ __align__(16) __bf16 Bs2[2][128][32];    // 16 KB (sub-major)
  __shared__ float sW[64], sB[64];

  const int bx = blockIdx.x;                        // 1024 blocks
  const int logical = (bx & 7) * 128 + (bx >> 3);   // bijective XCD swizzle
  const int tile_m = (logical >> 3) * 32;
  const int tile_n = (logical & 7) * 128;

  const int tid  = threadIdx.x;
  const int lane = tid & 63;
  const int wave = tid >> 6;
  const int wm = (wave >> 1) * 16;     // row half 0/16
  const int wn = (wave & 1) * 64;      // col half 0/64
  const int srow = lane >> 2;
  const int scol = (lane & 3) * 8;
  const int rl  = tid >> 3;            // local A row 0..31
  const int oct = tid & 7;             // column octet (8 cols each)

  if (tid < 64) { sW[tid] = lnw[tid]; sB[tid] = lnb[tid]; }

  const __bf16* obase = (const __bf16*)o + (size_t)(tile_m + rl) * 1024 + oct * 8;
  const __bf16* gbase = (const __bf16*)g + (size_t)(tile_m + rl) * 1024 + oct * 8;

  f32x4 acc[1][4];
#pragma unroll
  for (int j = 0; j < 4; ++j) acc[0][j] = {0.f, 0.f, 0.f, 0.f};

  // preload head 0 (8 cols per thread)
  bf16x8 ov0, gv0;
  ov0 = *(const bf16x8*)(obase);
  gv0 = *(const bf16x8*)(gbase);

  for (int h = 0; h < 16; ++h) {
    // issue NEXT head's o/g loads first (in flight across barriers + MFMA)
    bf16x8 no0, ng0;
    if (h + 1 < 16) {
      no0 = *(const bf16x8*)(obase + (h + 1) * 64);
      ng0 = *(const bf16x8*)(gbase + (h + 1) * 64);
    }

    __syncthreads();   // prior head's MFMA reads of As2/Bs2 complete

    // issue full 64-k B-slab stage for head h (both subs)
#pragma unroll
    for (int sub = 0; sub < 2; ++sub)
#pragma unroll
      for (int s = 0; s < 2; ++s) {
        int brow = tile_n + s * 64 + wave * 16 + srow;
        async_copy16((const __bf16*)Bw + (size_t)brow * 1024 + h * 64 + sub * 32 + scol,
                     &Bs2[sub][s * 64 + wave * 16 + srow][scol]);
      }

    // ---- LN + gate for head h -> As2 (row rl; 8 threads per row) ----
    float sum = 0.f;
#pragma unroll
    for (int e = 0; e < 8; ++e) sum += (float)ov0[e];
    sum += __shfl_xor(sum, 1);
    sum += __shfl_xor(sum, 2);
    sum += __shfl_xor(sum, 4);
    float mu = sum * (1.f / 64.f);
    float vv = 0.f;
#pragma unroll
    for (int e = 0; e < 8; ++e) {
      float d0 = (float)ov0[e] - mu;
      vv += d0 * d0;
    }
    vv += __shfl_xor(vv, 1);
    vv += __shfl_xor(vv, 2);
    vv += __shfl_xor(vv, 4);
    float rstd = rsqrtf(vv * (1.f / 64.f) + 1e-5f);

    bf16x8 res0;
#pragma unroll
    for (int e = 0; e < 8; ++e) {
      int c0 = oct * 8 + e;
      res0[e] = cvt_bf16((((float)ov0[e] - mu) * rstd * sW[c0] + sB[c0]) * (float)gv0[e]);
    }
    *(bf16x8*)&As2[rl][oct * 8] = res0;

    __syncthreads();               // Bs2 landed + As2 visible

#pragma unroll
    for (int sub = 0; sub < 2; ++sub) {
      bf16x8 af, bfr[4];
      af = *(const bf16x8*)&As2[wm + (lane & 15)][(lane >> 4) * 8 + sub * 32];
#pragma unroll
      for (int j = 0; j < 4; ++j)
        bfr[j] = *(const bf16x8*)&Bs2[sub][wn + j * 16 + (lane & 15)][(lane >> 4) * 8];

#pragma unroll
      for (int j = 0; j < 4; ++j)
        acc[0][j] = __builtin_amdgcn_mfma_f32_16x16x32_bf16(af, bfr[j], acc[0][j], 0, 0, 0);
    }

    if (h + 1 < 16) { ov0 = no0; gv0 = ng0; }
  }

#pragma unroll
  for (int j = 0; j < 4; ++j)
#pragma unroll
    for (int r = 0; r < 4; ++r) {
      int gm = tile_m + wm + (lane >> 4) * 4 + r;
      int gn = tile_n + wn + j * 16 + (lane & 15);
      C[(size_t)gm * 1024 + gn] = acc[0][j][r];
    }
}

// Fused 4-projection + beta GEMM. 1-D grid 1056 blocks:
//  bx < 1024: GEMM tiles; XCD partition = 8m x 16n per XCD.
//  bx >= 1024: beta tiles.
__global__ __launch_bounds__(256) void mega_gemm2(
    const bf16* __restrict__ Av, const bf16* __restrict__ W4b,
    const float* __restrict__ Wb, const float* __restrict__ bb,
    const float* __restrict__ ba, bf16* __restrict__ C4,
    float* __restrict__ betab)
{
  __shared__ __align__(16) __bf16 As[128 * 32];
  __shared__ __align__(16) __bf16 Bs[128 * 32];

  const int bx = blockIdx.x;
  const bool isbeta = (bx >= 1024);
  int tile_m, tile_n;
  if (!isbeta) {
    const int xcd = bx & 7;
    const int local = bx >> 3;        // 0..127
    const int mg = xcd >> 1;          // 0..3 (M groups of 8)
    const int ng = xcd & 1;           // 0..1 (N groups of 16)
    const int lm = local & 7;         // 0..7
    const int ln = local >> 3;        // 0..15
    tile_m = (mg * 8 + lm) * 128;
    tile_n = (ng * 16 + ln) * 128;
  } else {
    tile_m = (bx - 1024) * 128;
    tile_n = 0;
  }
  const int grp = tile_n >> 10;
  const int tnl = tile_n & 1023;

  const int tid  = threadIdx.x;
  const int lane = tid & 63;
  const int wave = tid >> 6;
  const int wm = (wave >> 1) * 64;
  const int wn = (wave & 1) * 64;

  const int srow = lane >> 2;
  const int scol = (lane & 3) * 8;

  f32x4 acc[4][4];
#pragma unroll
  for (int i = 0; i < 4; ++i)
#pragma unroll
    for (int j = 0; j < 4; ++j) acc[i][j] = {0.f, 0.f, 0.f, 0.f};

  const __bf16* Wp = (const __bf16*)W4b + (size_t)grp * 1024 * 1024;

  for (int k0 = 0; k0 < 1024; k0 += 32) {
    float4 b0[2], b1[2];
    if (isbeta) {
#pragma unroll
      for (int s = 0; s < 2; ++s) {
        int brow = s * 64 + wave * 16 + srow;
        if (brow > 15) brow = 15;
        const float* bp = Wb + (size_t)brow * 1024 + k0 + scol;
        b0[s] = *(const float4*)bp;
        b1[s] = *(const float4*)(bp + 4);
      }
    }
    __syncthreads();
#pragma unroll
    for (int s = 0; s < 2; ++s) {
      int arow = tile_m + s * 64 + wave * 16 + srow;
      async_copy16((const __bf16*)Av + (size_t)arow * 1024 + k0 + scol,
                   &As[(s * 64 + wave * 16 + srow) * 32 + scol]);
      if (!isbeta) {
        int brow = tnl + s * 64 + wave * 16 + srow;
        async_copy16(Wp + (size_t)brow * 1024 + k0 + scol,
                     &Bs[(s * 64 + wave * 16 + srow) * 32 + scol]);
      } else {
        bf16x8 u;
        u[0] = cvt_bf16(b0[s].x); u[1] = cvt_bf16(b0[s].y);
        u[2] = cvt_bf16(b0[s].z); u[3] = cvt_bf16(b0[s].w);
        u[4] = cvt_bf16(b1[s].x); u[5] = cvt_bf16(b1[s].y);
        u[6] = cvt_bf16(b1[s].z); u[7] = cvt_bf16(b1[s].w);
        *(bf16x8*)&Bs[(s * 64 + wave * 16 + srow) * 32 + scol] = u;
      }
    }
    __syncthreads();

    bf16x8 af[4], bfr[4];
#pragma unroll
    for (int i = 0; i < 4; ++i)
      af[i] = *(const bf16x8*)&As[(wm + i * 16 + (lane & 15)) * 32 + (lane >> 4) * 8];
#pragma unroll
    for (int j = 0; j < 4; ++j)
      bfr[j] = *(const bf16x8*)&Bs[(wn + j * 16 + (lane & 15)) * 32 + (lane >> 4) * 8];

#pragma unroll
    for (int i = 0; i < 4; ++i)
#pragma unroll
      for (int j = 0; j < 4; ++j)
        acc[i][j] = __builtin_amdgcn_mfma_f32_16x16x32_bf16(af[i], bfr[j], acc[i][j], 0, 0, 0);
  }

  if (!isbeta) {
    bf16* Cp = (bf16*)((__bf16*)C4 + (size_t)grp * 4096 * 1024);
#pragma unroll
    for (int i = 0; i < 4; ++i)
#pragma unroll
      for (int j = 0; j < 4; ++j)
#pragma unroll
        for (int r = 0; r < 4; ++r) {
          int gm = tile_m + wm + i * 16 + (lane >> 4) * 4 + r;
          int col = tnl + wn + j * 16 + (lane & 15);
          float val = acc[i][j][r];
          if (grp == 3) val = 1.f / (1.f + __expf(-(val + ba[col])));
          ((__bf16*)Cp)[(size_t)gm * 1024 + col] = cvt_bf16(val);
        }
  } else {
#pragma unroll
    for (int i = 0; i < 4; ++i)
#pragma unroll
      for (int j = 0; j < 4; ++j)
#pragma unroll
        for (int r = 0; r < 4; ++r) {
          int gm = tile_m + wm + i * 16 + (lane >> 4) * 4 + r;
          int gn = wn + j * 16 + (lane & 15);
          if (gn < 16) {
            float val = 1.f / (1.f + __expf(-(acc[i][j][r] + bb[gn])));
            betab[(size_t)gn * 4096 + gm] = val;
          }
        }
  }
}

// shared conv body: causal depthwise K=4 + bias + SiLU (+scale), x8 vec.
__device__ __forceinline__ void conv_body(
    int idx, const bf16* __restrict__ z, const float* __restrict__ w,
    const float* __restrict__ bias, bf16* __restrict__ out, float scale)
{
  int c8 = idx & 127;
  int m  = idx >> 7;
  int t  = m & 2047;
  int c0 = c8 * 8;

  const __bf16* base = (const __bf16*)z + (size_t)m * 1024 + c0;
  const bf16x8 zzero = __builtin_bit_cast(bf16x8, (u32x4){0u, 0u, 0u, 0u});
  bf16x8 z3 = *(const bf16x8*)base;
  bf16x8 z2 = (t >= 1) ? *(const bf16x8*)(base - 1024) : zzero;
  bf16x8 z1 = (t >= 2) ? *(const bf16x8*)(base - 2048) : zzero;
  bf16x8 z0 = (t >= 3) ? *(const bf16x8*)(base - 3072) : zzero;

  const float* wp = w + c0 * 4;
  bf16x8 res;
#pragma unroll
  for (int e = 0; e < 8; ++e) {
    float4 we = *(const float4*)(wp + e * 4);
    float acc = bias[c0 + e] + (float)z3[e] * we.w;
    acc += (float)z2[e] * we.z;
    acc += (float)z1[e] * we.y;
    acc += (float)z0[e] * we.x;
    float s = acc / (1.f + __expf(-acc));
    res[e] = cvt_bf16(s * scale);
  }
  *(bf16x8*)((__bf16*)out + (size_t)m * 1024 + c0) = res;
}

// standalone conv
__global__ __launch_bounds__(256) void conv_silu_kernel(
    const bf16* __restrict__ z, const float* __restrict__ w,
    const float* __restrict__ bias, bf16* __restrict__ out, float scale)
{
  conv_body(blockIdx.x * 256 + threadIdx.x, z, w, bias, out, scale);
}

// conv_q + (conv_k + fused kk) in one launch. Grid 4096.
// k-section: recompute k[t-1] in-register (bit-identical bf16), 8-lane
// shfl dot over the head-octet, write G = beta * (k_{t-1}.k_t).
__global__ __launch_bounds__(256) void conv2_kernel(
    const bf16* __restrict__ zq, const bf16* __restrict__ zk,
    const float* __restrict__ qcw, const float* __restrict__ qcb,
    const float* __restrict__ kcw, const float* __restrict__ kcb,
    bf16* __restrict__ oq, bf16* __restrict__ ok,
    const float* __restrict__ betab, float* __restrict__ G)
{
  int sec = blockIdx.x >> 11;
  int bx  = blockIdx.x & 2047;
  int idx = bx * 256 + threadIdx.x;
  if (sec == 0) { conv_body(idx, zq, qcw, qcb, oq, 1.f); return; }

  // ---- conv_k + kk ----
  int c8 = idx & 127;
  int m  = idx >> 7;
  int t  = m & 2047;
  int c0 = c8 * 8;

  const __bf16* base = (const __bf16*)zk + (size_t)m * 1024 + c0;
  const bf16x8 zzero = __builtin_bit_cast(bf16x8, (u32x4){0u, 0u, 0u, 0u});
  bf16x8 z3 = *(const bf16x8*)base;
  bf16x8 z2 = (t >= 1) ? *(const bf16x8*)(base - 1024) : zzero;
  bf16x8 z1 = (t >= 2) ? *(const bf16x8*)(base - 2048) : zzero;
  bf16x8 z0 = (t >= 3) ? *(const bf16x8*)(base - 3072) : zzero;
  bf16x8 zm4 = (t >= 4) ? *(const bf16x8*)(base - 4096) : zzero;

  const float* wp = kcw + c0 * 4;
  bf16x8 res;
  float dot = 0.f;
#pragma unroll
  for (int e = 0; e < 8; ++e) {
    float4 we = *(const float4*)(wp + e * 4);
    float acc = kcb[c0 + e] + (float)z3[e] * we.w;
    acc += (float)z2[e] * we.z;
    acc += (float)z1[e] * we.y;
    acc += (float)z0[e] * we.x;
    float s = acc / (1.f + __expf(-acc));
    res[e] = cvt_bf16(s * 0.125f);
  }
  *(bf16x8*)((__bf16*)ok + (size_t)m * 1024 + c0) = res;

  if (t >= 1) {
#pragma unroll
    for (int e = 0; e < 8; ++e) {
      float4 we = *(const float4*)(wp + e * 4);
      float accp = kcb[c0 + e] + (float)z2[e] * we.w;
      accp += (float)z1[e] * we.z;
      accp += (float)z0[e] * we.y;
      accp += (float)zm4[e] * we.x;
      float sp = accp / (1.f + __expf(-accp));
      __bf16 rp = cvt_bf16(sp * 0.125f);
      dot += (float)rp * (float)res[e];
    }
  }
  dot += __shfl_xor(dot, 1);
  dot += __shfl_xor(dot, 2);
  dot += __shfl_xor(dot, 4);
  if ((threadIdx.x & 7) == 0) {
    int h = c0 >> 6;
    G[(size_t)h * 4096 + m] = betab[(size_t)h * 4096 + m] * dot;
  }
}

// kk standalone (fallback)
__global__ __launch_bounds__(256) void kk_kernel(
    const bf16* __restrict__ k, const float* __restrict__ betab,
    float* __restrict__ G)
{
  int tid = blockIdx.x * 256 + threadIdx.x;
  int out = tid >> 2;
  int j   = tid & 3;
  int h = out >> 12;
  int m = out & 4095;
  int t = m & 2047;
  float s = 0.f;
  if (t > 0) {
    const __bf16* r1 = (const __bf16*)k + (size_t)m * 1024 + h * 64 + j * 16;
    const __bf16* r0 = r1 - 1024;
    bf16x8 a0 = *(const bf16x8*)r0;
    bf16x8 a1 = *(const bf16x8*)(r0 + 8);
    bf16x8 b0 = *(const bf16x8*)r1;
    bf16x8 b1 = *(const bf16x8*)(r1 + 8);
#pragma unroll
    for (int e = 0; e < 8; ++e)
      s += (float)a0[e] * (float)b0[e] + (float)a1[e] * (float)b1[e];
  }
  s += __shfl_xor(s, 1);
  s += __shfl_xor(s, 2);
  if (j == 0) G[out] = betab[out] * s;
}

// One scan step (constant word indices only).
#define SCAN_STEP(i, KN0, KN1, Q0, Q1, WV, WA, BT, GT, LAST)                  \
  {                                                                           \
    const float vr = ((i) & 1) ? bcf((WV) & 0xffff0000u) : bcf((WV) << 16);   \
    const float ar = ((i) & 1) ? bcf((WA) & 0xffff0000u) : bcf((WA) << 16);   \
    float unxt = 0.f;                                                         \
    f32x2 k2n0 = {0.f, 0.f}, k2n1 = {0.f, 0.f};                               \
    if (!(LAST)) {                                                            \
      k2n0 = unpk(KN0); k2n1 = unpk(KN1);                                     \
      f32x2 dd = S20 * k2n0; dd += S21 * k2n1;                                \
      unxt = dd[0] + dd[1];                                                   \
      unxt += dpp_f<0xB1>(unxt);  unxt += dpp_f<0x4E>(unxt);                  \
      unxt += dpp_f<0x141>(unxt); unxt += dpp_f<0x140>(unxt);                 \
    } else { Sold0 = S20; Sold1 = S21; }                                      \
    float A_ = (BT) * __builtin_fmaf(aprev, u, -vr);                          \
    cc = __builtin_fmaf(-cc, (GT), A_);                                       \
    f32x2 q20 = unpk(Q0), q21 = unpk(Q1);                                     \
    const f32x2 cc2 = {cc, cc}, arv = {ar, ar};                               \
    f32x2 oo;                                                                 \
    { f32x2 t0 = cc2 * k2c0; S20 = arv * S20 - t0; oo = S20 * q20;            \
      f32x2 t1 = cc2 * k2c1; S21 = arv * S21 - t1; oo += S21 * q21; }         \
    so[(i)][lane] = oo[0] + oo[1];                                            \
    aprev = ar;                                                               \
    if (!(LAST)) { k2c0 = k2n0; k2c1 = k2n1; u = unxt; }                      \
  }

// Load one 2-step group (g = 0..7) into a named set (14 regs).
#define LOADG(KS, QS, VS, AS, BS, GS, g)                                      \
  KS = *(const u32x4*)&skT[buf][sg][(g) * 8];                                 \
  QS = *(const u32x4*)&sqT[buf][sg][(g) * 8];                                 \
  VS = *(const unsigned int*)&svaT[buf][0][r4][(g) * 2];                      \
  AS = *(const unsigned int*)&svaT[buf][1][r4][(g) * 2];                      \
  BS = *(const f32x2*)&sbeta[c * 16 + (g) * 2];                               \
  GS = *(const f32x2*)&sG[c * 16 + (g) * 2];

// FUSED kernel: blocks 0..511 = delta-rule scan (single wave; threads>=64
// exit; NO barriers; s_setprio(1)). Blocks 512..767 = g-GEMM.
__global__ __launch_bounds__(256) void scan_gemm_kernel(
    const bf16* __restrict__ q, const bf16* __restrict__ k,
    const bf16* __restrict__ v, const bf16* __restrict__ a,
    const float* __restrict__ betab, const float* __restrict__ gkk,
    bf16* __restrict__ o,
    const float* __restrict__ x, const bf16* __restrict__ Wgb,
    bf16* __restrict__ gout)
{
  __shared__ __align__(16) __bf16 skT[2][16][72];
  __shared__ __align__(16) __bf16 sqT[2][16][72];
  __shared__ __align__(16) __bf16 svaT[2][2][4][16];
  __shared__ __align__(16) float  so[16][68];
  __shared__ __align__(16) __bf16 so2[16][4];
  __shared__ float sbeta[2048];
  __shared__ float sG[2048];
  __shared__ __align__(16) __bf16 As[128 * 32];
  __shared__ __align__(16) __bf16 Bs[128 * 32];

  if (blockIdx.x >= 512) {
    const int gb   = blockIdx.x - 512;
    const int tid  = threadIdx.x;
    const int lane = tid & 63;
    const int wave = tid >> 6;
    const int tile_m = (gb >> 3) * 128;
    const int tile_n = (gb & 7) * 128;
    const int wm = (wave >> 1) * 64;
    const int wn = (wave & 1) * 64;
    const int srow = lane >> 2;
    const int scol = (lane & 3) * 8;

    f32x4 acc[4][4];
#pragma unroll
    for (int i = 0; i < 4; ++i)
#pragma unroll
      for (int j = 0; j < 4; ++j) acc[i][j] = {0.f, 0.f, 0.f, 0.f};

    for (int k0 = 0; k0 < 1024; k0 += 32) {
      float4 a0[2], a1[2];
#pragma unroll
      for (int s = 0; s < 2; ++s) {
        int arow = tile_m + s * 64 + wave * 16 + srow;
        const float* ap = x + (size_t)arow * 1024 + k0 + scol;
        a0[s] = *(const float4*)ap;
        a1[s] = *(const float4*)(ap + 4);
      }
      __syncthreads();
#pragma unroll
      for (int s = 0; s < 2; ++s) {
        bf16x8 ua;
        ua[0] = cvt_bf16(a0[s].x); ua[1] = cvt_bf16(a0[s].y);
        ua[2] = cvt_bf16(a0[s].z); ua[3] = cvt_bf16(a0[s].w);
        ua[4] = cvt_bf16(a1[s].x); ua[5] = cvt_bf16(a1[s].y);
        ua[6] = cvt_bf16(a1[s].z); ua[7] = cvt_bf16(a1[s].w);
        *(bf16x8*)&As[(s * 64 + wave * 16 + srow) * 32 + scol] = ua;
        int brow = tile_n + s * 64 + wave * 16 + srow;
        async_copy16((const __bf16*)Wgb + (size_t)brow * 1024 + k0 + scol,
                     &Bs[(s * 64 + wave * 16 + srow) * 32 + scol]);
      }
      __syncthreads();

      bf16x8 af[4], bfr[4];
#pragma unroll
      for (int i = 0; i < 4; ++i)
        af[i] = *(const bf16x8*)&As[(wm + i * 16 + (lane & 15)) * 32 + (lane >> 4) * 8];
#pragma unroll
      for (int j = 0; j < 4; ++j)
        bfr[j] = *(const bf16x8*)&Bs[(wn + j * 16 + (lane & 15)) * 32 + (lane >> 4) * 8];

#pragma unroll
      for (int i = 0; i < 4; ++i)
#pragma unroll
        for (int j = 0; j < 4; ++j)
          acc[i][j] = __builtin_amdgcn_mfma_f32_16x16x32_bf16(af[i], bfr[j], acc[i][j], 0, 0, 0);
    }

#pragma unroll
    for (int i = 0; i < 4; ++i)
#pragma unroll
      for (int j = 0; j < 4; ++j)
#pragma unroll
        for (int r = 0; r < 4; ++r) {
          int gm = tile_m + wm + i * 16 + (lane >> 4) * 4 + r;
          int gn = tile_n + wn + j * 16 + (lane & 15);
          float val = 1.f / (1.f + __expf(-acc[i][j][r]));
          gout[(size_t)gm * 1024 + gn] = (bf16)val;
        }
    return;
  }

  // ---------------- scan path (single wave; extra waves exit) ----------------
  if (threadIdx.x >= 64) return;
  __builtin_amdgcn_s_setprio(1);

  const int blk = blockIdx.x;
  const int qd = blk >> 5;
  const int bh = blk & 31;
  const int b = bh >> 4, h = bh & 15;
  const int lane = threadIdx.x;
  const int r4 = lane >> 4;
  const int sg = lane & 15;

  {
    const float* bp = betab + (size_t)h * 4096 + b * 2048;
    const float* gp = gkk   + (size_t)h * 4096 + b * 2048;
    for (int t4 = lane * 4; t4 < 2048; t4 += 256) {
      *(float4*)&sbeta[t4] = *(const float4*)(bp + t4);
      *(float4*)&sG[t4]    = *(const float4*)(gp + t4);
    }
  }

  const size_t bkq = (size_t)b * 2048 * 1024 + h * 64;
  const size_t bva = bkq + qd * 4;
  const __bf16* kp = (const __bf16*)k;
  const __bf16* qp = (const __bf16*)q;

  const int g_st = lane >> 3;
  const int g_cg = (lane & 7) * 8;
  const int sgp  = (lane & 7) * 2;
  const int va_vh = (lane >> 4) & 1;
  const int va_st = lane & 15;

  bf16x8 pk0, pk1, pq0, pq1;
  bf16x4v pva;
  auto fetch = [&](int t0) {
    int st0 = t0 + g_st, st1 = t0 + 8 + g_st;
    pk0 = *(const bf16x8*)(kp + bkq + (size_t)st0 * 1024 + g_cg);
    pk1 = *(const bf16x8*)(kp + bkq + (size_t)st1 * 1024 + g_cg);
    pq0 = *(const bf16x8*)(qp + bkq + (size_t)st0 * 1024 + g_cg);
    pq1 = *(const bf16x8*)(qp + bkq + (size_t)st1 * 1024 + g_cg);
    if (lane < 32) {
      const __bf16* src = va_vh ? (const __bf16*)a : (const __bf16*)v;
      pva = *(const bf16x4v*)(src + bva + (size_t)(t0 + va_st) * 1024);
    }
  };
  auto commit = [&](int cb) {
    {
      u32x4 wk = __builtin_bit_cast(u32x4, pk0);
      u32x4 wq = __builtin_bit_cast(u32x4, pq0);
      u32x2 lo, hi;
      lo[0] = wk[0]; lo[1] = wk[1]; hi[0] = wk[2]; hi[1] = wk[3];
      *(u32x2*)&skT[cb][sgp][g_st * 4]     = lo;
      *(u32x2*)&skT[cb][sgp + 1][g_st * 4] = hi;
      lo[0] = wq[0]; lo[1] = wq[1]; hi[0] = wq[2]; hi[1] = wq[3];
      *(u32x2*)&sqT[cb][sgp][g_st * 4]     = lo;
      *(u32x2*)&sqT[cb][sgp + 1][g_st * 4] = hi;
    }
    {
      u32x4 wk = __builtin_bit_cast(u32x4, pk1);
      u32x4 wq = __builtin_bit_cast(u32x4, pq1);
      u32x2 lo, hi;
      lo[0] = wk[0]; lo[1] = wk[1]; hi[0] = wk[2]; hi[1] = wk[3];
      *(u32x2*)&skT[cb][sgp][(8 + g_st) * 4]     = lo;
      *(u32x2*)&skT[cb][sgp + 1][(8 + g_st) * 4] = hi;
      lo[0] = wq[0]; lo[1] = wq[1]; hi[0] = wq[2]; hi[1] = wq[3];
      *(u32x2*)&sqT[cb][sgp][(8 + g_st) * 4]     = lo;
      *(u32x2*)&sqT[cb][sgp + 1][(8 + g_st) * 4] = hi;
    }
    if (lane < 32) {
#pragma unroll
      for (int r = 0; r < 4; ++r) svaT[cb][va_vh][r][va_st] = pva[r];
    }
  };

  fetch(0); commit(0);

  f32x2 S20 = {0.f, 0.f}, S21 = {0.f, 0.f};
  f32x2 Sold0 = {0.f, 0.f}, Sold1 = {0.f, 0.f};
  float u = 0.f, cc = 0.f, aprev = 0.f;

  auto unpk = [&](unsigned int w) -> f32x2 {
    f32x2 r; r[0] = bcf(w << 16); r[1] = bcf(w & 0xffff0000u); return r;
  };

  for (int c = 0; c < 128; ++c) {
    const int buf = c & 1;
    const bool hasNext = (c + 1 < 128);

    if (hasNext) fetch((c + 1) * 16);

    u32x4 kA, qA, kB, qB, kC, qC;
    unsigned int vA, aA, vB, aB, vC, aC;
    f32x2 bA, gA, bB, gB, bC, gC;

    LOADG(kA, qA, vA, aA, bA, gA, 0)
    LOADG(kB, qB, vB, aB, bB, gB, 1)
    LOADG(kC, qC, vC, aC, bC, gC, 2)

    f32x2 k2c0 = unpk(kA[0]);
    f32x2 k2c1 = unpk(kA[1]);
    {
      f32x2 dd = Sold0 * k2c0;
      dd += Sold1 * k2c1;
      float un = dd[0] + dd[1];
      un += dpp_f<0xB1>(un);
      un += dpp_f<0x4E>(un);
      un += dpp_f<0x141>(un);
      un += dpp_f<0x140>(un);
      u = un;
    }

    SCAN_STEP(0,  kA[2], kA[3], qA[0], qA[1], vA, aA, bA[0], gA[0], false)
    SCAN_STEP(1,  kB[0], kB[1], qA[2], qA[3], vA, aA, bA[1], gA[1], false)
    LOADG(kA, qA, vA, aA, bA, gA, 3)
    SCAN_STEP(2,  kB[2], kB[3], qB[0], qB[1], vB, aB, bB[0], gB[0], false)
    SCAN_STEP(3,  kC[0], kC[1], qB[2], qB[3], vB, aB, bB[1], gB[1], false)
    LOADG(kB, qB, vB, aB, bB, gB, 4)
    SCAN_STEP(4,  kC[2], kC[3], qC[0], qC[1], vC, aC, bC[0], gC[0], false)
    SCAN_STEP(5,  kA[0], kA[1], qC[2], qC[3], vC, aC, bC[1], gC[1], false)
    LOADG(kC, qC, vC, aC, bC, gC, 5)
    SCAN_STEP(6,  kA[2], kA[3], qA[0], qA[1], vA, aA, bA[0], gA[0], false)
    SCAN_STEP(7,  kB[0], kB[1], qA[2], qA[3], vA, aA, bA[1], gA[1], false)
    LOADG(kA, qA, vA, aA, bA, gA, 6)
    SCAN_STEP(8,  kB[2], kB[3], qB[0], qB[1], vB, aB, bB[0], gB[0], false)
    SCAN_STEP(9,  kC[0], kC[1], qB[2], qB[3], vB, aB, bB[1], gB[1], false)
    LOADG(kB, qB, vB, aB, bB, gB, 7)
    SCAN_STEP(10, kC[2], kC[3], qC[0], qC[1], vC, aC, bC[0], gC[0], false)
    SCAN_STEP(11, kA[0], kA[1], qC[2], qC[3], vC, aC, bC[1], gC[1], false)
    SCAN_STEP(12, kA[2], kA[3], qA[0], qA[1], vA, aA, bA[0], gA[0], false)
    SCAN_STEP(13, kB[0], kB[1], qA[2], qA[3], vA, aA, bA[1], gA[1], false)
    SCAN_STEP(14, kB[2], kB[3], qB[0], qB[1], vB, aB, bB[0], gB[0], false)
    SCAN_STEP(15, kB[2], kB[3], qB[2], qB[3], vB, aB, bB[1], gB[1], true)

    {
      int st = lane >> 2, rr = lane & 3;
      float4 A0 = *(const float4*)&so[st][rr * 16];
      float4 A1 = *(const float4*)&so[st][rr * 16 + 4];
      float4 A2 = *(const float4*)&so[st][rr * 16 + 8];
      float4 A3 = *(const float4*)&so[st][rr * 16 + 12];
      float s = (((A0.x + A0.y) + (A0.z + A0.w)) + ((A1.x + A1.y) + (A1.z + A1.w)))
              + (((A2.x + A2.y) + (A2.z + A2.w)) + ((A3.x + A3.y) + (A3.z + A3.w)));
      so2[st][rr] = cvt_bf16(s);
    }
    if (lane < 16)
      *(bf16x4v*)((__bf16*)o + bva + (size_t)(c * 16 + lane) * 1024) =
          *(const bf16x4v*)&so2[lane][0];

    if (hasNext) commit(buf ^ 1);
  }
}

// LayerNorm over DV=64 per (b,t,h) row, *ln_w+ln_b, *gate -> bf16 (fallback)
__global__ __launch_bounds__(256) void ln_gate_kernel(
    const bf16* __restrict__ o, const bf16* __restrict__ g,
    const float* __restrict__ lnw, const float* __restrict__ lnb,
    bf16* __restrict__ out)
{
  int row = blockIdx.x * 4 + (threadIdx.x >> 6);
  int lane = threadIdx.x & 63;
  size_t idx = (size_t)row * 64 + lane;
  float xv = (float)o[idx];
  float mu = xv;
#pragma unroll
  for (int s = 1; s < 64; s <<= 1) mu += __shfl_xor(mu, s);
  mu *= (1.f / 64.f);
  float d = xv - mu;
  float vv = d * d;
#pragma unroll
  for (int s = 1; s < 64; s <<= 1) vv += __shfl_xor(vv, s);
  vv *= (1.f / 64.f);
  float y = d * rsqrtf(vv + 1e-5f) * lnw[lane] + lnb[lane];
  y *= (float)g[idx];
  out[idx] = (bf16)y;
}

extern "C" void kernel_launch(void* const* d_in, const int* in_sizes, int n_in,
                              void* d_out, int out_size, void* d_ws, size_t ws_size,
                              hipStream_t stream)
{
  const float* x   = (const float*)d_in[0];
  const float* Wq  = (const float*)d_in[1];
  const float* Wk  = (const float*)d_in[2];
  const float* Wv  = (const float*)d_in[3];
  const float* Wa  = (const float*)d_in[4];
  const float* ba  = (const float*)d_in[5];
  const float* Wb  = (const float*)d_in[6];
  const float* bb  = (const float*)d_in[7];
  const float* Wg  = (const float*)d_in[8];
  const float* Wo  = (const float*)d_in[9];
  const float* qcw = (const float*)d_in[10];
  const float* qcb = (const float*)d_in[11];
  const float* kcw = (const float*)d_in[12];
  const float* kcb = (const float*)d_in[13];
  const float* vcw = (const float*)d_in[14];
  const float* vcb = (const float*)d_in[15];
  const float* lnw = (const float*)d_in[16];
  const float* lnb = (const float*)d_in[17];

  const int M = 4096, HID = 1024;
  const size_t PLANE = (size_t)M * HID;
  const size_t PB = PLANE * sizeof(bf16);          // 8 MB bf16 plane

  char* ws = (char*)d_ws;
  float* outf = (float*)d_out;
  const bool rich = (ws_size >= 5 * PB + 1024);

  dim3 blk(256);
  dim3 g8(8, 32);
  int nconv = (int)((size_t)M * 128 / 256);

  if (rich) {
    bf16* P0 = (bf16*)(ws);
    bf16* P1 = (bf16*)(ws + PB);
    bf16* P2 = (bf16*)(ws + 2 * PB);
    bf16* P3 = (bf16*)(ws + 3 * PB);
    bf16* P4 = (bf16*)(ws + 4 * PB);
    bf16*  xb    = (bf16*)d_out;                            // [0,8M)
    bf16*  W4b   = (bf16*)((char*)d_out + 8 * 1024 * 1024); // [8M,16M)
    bf16*  Kb    = xb;                                      // k-plane
    bf16*  Qb    = W4b;                                     // q-plane
    float* betab = (float*)P4;
    float* gkk   = (float*)((char*)P4 + 256 * 1024);
    bf16*  Wgb   = (bf16*)((char*)P4 + 1024 * 1024);
    bf16*  Wob   = (bf16*)((char*)P4 + 3 * 1024 * 1024);

    // 1. convert x + 6 weight matrices to bf16
    cvtw_kernel<<<10240, blk, 0, stream>>>(x, Wq, Wk, Wv, Wa, Wg, Wo,
                                           xb, W4b, Wgb, Wob);
    // 2. fused 4-projection + beta GEMM (1-D grid, 8m x 16n per-XCD partition)
    mega_gemm2<<<1056, blk, 0, stream>>>(xb, W4b, Wb, bb, ba, P0, betab);
    // 3. conv q (P0->Qb) + conv k (P1->Kb) with fused kk (G->gkk)
    conv2_kernel<<<4096, blk, 0, stream>>>(P0, P1, qcw, qcb, kcw, kcb, Qb, Kb,
                                           betab, gkk);
    // 4. conv v (P2->P1)
    conv_silu_kernel<<<2048, blk, 0, stream>>>(P2, vcw, vcb, P1, 1.f);
    // 5. FUSED scan (o->P0) + g-GEMM (sigmoid(x@Wgb^T)->P2)
    scan_gemm_kernel<<<768, blk, 0, stream>>>(Qb, Kb, P1, P3, betab, gkk, P0,
                                              x, Wgb, P2);
    // 6. final GEMM with fused LN+gate (1024 blocks = 4/CU, XCD swizzle,
    //    full-64k B staging)
    gemm_bb_ln<<<1024, blk, 0, stream>>>(P0, P2, lnw, lnb, Wob, outf);
  } else {
    bf16* P  = (bf16*)(ws);
    bf16* qb = (bf16*)(ws + PB);
    bf16* kb = (bf16*)(ws + 2 * PB);
    bf16* vb = (bf16*)(ws + 3 * PB);
    float* betab = (float*)d_out;
    float* gkk   = (float*)((char*)d_out + 256 * 1024);
    bf16*  ob    = (bf16*)((char*)d_out + 8 * 1024 * 1024);

    gemm_bt<2, true><<<g8, blk, 0, stream>>>(x, Wq, nullptr, nullptr, P, M, HID, HID);
    conv_silu_kernel<<<nconv, blk, 0, stream>>>(P, qcw, qcb, qb, 1.f);
    gemm_bt<2, true><<<g8, blk, 0, stream>>>(x, Wk, nullptr, nullptr, P, M, HID, HID);
    conv_silu_kernel<<<nconv, blk, 0, stream>>>(P, kcw, kcb, kb, 0.125f);
    gemm_bt<2, true><<<g8, blk, 0, stream>>>(x, Wv, nullptr, nullptr, P, M, HID, HID);
    conv_silu_kernel<<<nconv, blk, 0, stream>>>(P, vcw, vcb, vb, 1.f);
    gemm_bt<3, true><<<g8, blk, 0, stream>>>(x, Wa, ba, nullptr, P, M, HID, HID);
    gemm_bt<5, true><<<dim3(1, 32), blk, 0, stream>>>(x, Wb, bb, betab, nullptr, M, 16, HID);
    kk_kernel<<<1024, blk, 0, stream>>>(kb, betab, gkk);
    scan_gemm_kernel<<<512, blk, 0, stream>>>(qb, kb, vb, P, betab, gkk, ob,
                                              x, nullptr, nullptr);
    gemm_bt<3, true><<<g8, blk, 0, stream>>>(x, Wg, nullptr, nullptr, qb, M, HID, HID);
    ln_gate_kernel<<<M * 16 / 4, blk, 0, stream>>>(ob, qb, lnw, lnb, kb);
    gemm_bt<4, false><<<g8, blk, 0, stream>>>(kb, Wo, nullptr, outf, nullptr, M, HID, HID);
  }
}

// Round 17
// 428.681 us; speedup vs baseline: 1.0293x; 1.0293x over previous
//
#include <hip/hip_runtime.h>
#include <hip/hip_bf16.h>
#include <cstdint>

// B=2, T=2048, HID=1024, H=16, DK=DV=64, K(conv)=4. fp32 in/out.
// RICH memory plan (ws >= 40MB): ws = P0..P4 (8MB bf16 planes).
//  d_out[0,8M): xb -> Kb (k-plane);  d_out[8M,16M): W4b -> Qb (q-plane)
//  P4: [0,256K) betab fp32; [256K,512K) gkk; [1M,3M) Wgb; [3M,5M) Wob
//  P0: zq -> scan o;  P1: zk -> v-plane;  P2: zv -> g-plane;  P3: a plane
// Launches (6): cvtw -> mega_gemm2(+beta) -> conv2(q,k) -> convv_kk
//   -> FUSED scan+g-GEMM -> gemm_bb_ln.
//
// R17: exact revert to R15 (428us best). R16's kk-in-conv fusion (2x conv_k
// VALU incl. second expf) and 1024-block bb_ln (2x Wob traffic) regressed
// -13us; both dropped. This is the proven best-known configuration.

using bf16 = __hip_bfloat16;
typedef __bf16 bf16x8 __attribute__((ext_vector_type(8)));
typedef __bf16 bf16x4v __attribute__((ext_vector_type(4)));
typedef float f32x4 __attribute__((ext_vector_type(4)));
typedef float f32x2 __attribute__((ext_vector_type(2)));
typedef unsigned int u32x4 __attribute__((ext_vector_type(4)));
typedef unsigned int u32x2 __attribute__((ext_vector_type(2)));

__device__ __forceinline__ __bf16 cvt_bf16(float f) {
  __hip_bfloat16 h = (__hip_bfloat16)f;
  return *reinterpret_cast<__bf16*>(&h);
}
__device__ __forceinline__ void async_copy16(const void* g, void* l) {
  __builtin_amdgcn_global_load_lds((const __attribute__((address_space(1))) void*)g,
                                   (__attribute__((address_space(3))) void*)l,
                                   16, 0, 0);
}
__device__ __forceinline__ float bcf(unsigned int u) { return __builtin_bit_cast(float, u); }
template <int CTRL>
__device__ __forceinline__ float dpp_f(float x) {
  int y = __builtin_amdgcn_update_dpp(0, __builtin_bit_cast(int, x), CTRL, 0xF, 0xF, true);
  return __builtin_bit_cast(float, y);
}

// fp32 -> bf16: x (blocks 0..4095), W4 (4096..8191), Wg (8192..9215),
// Wo (9216..10239).
__global__ __launch_bounds__(256) void cvtw_kernel(
    const float* __restrict__ x, const float* __restrict__ Wq,
    const float* __restrict__ Wk, const float* __restrict__ Wv,
    const float* __restrict__ Wa, const float* __restrict__ Wg,
    const float* __restrict__ Wo, bf16* __restrict__ xb,
    bf16* __restrict__ w4b, bf16* __restrict__ wgb, bf16* __restrict__ wob)
{
  int blk = blockIdx.x;
  const float* src;
  __bf16* dst;
  size_t off;
  if (blk < 4096) {
    src = x; dst = (__bf16*)xb;
    off = (size_t)blk * 1024 + threadIdx.x * 4;
  } else if (blk < 8192) {
    int wb = blk - 4096;
    int wi = wb >> 10;
    src = (wi == 0) ? Wq : (wi == 1) ? Wk : (wi == 2) ? Wv : Wa;
    dst = (__bf16*)w4b + (size_t)wi * 1024 * 1024;
    off = (size_t)(wb & 1023) * 1024 + threadIdx.x * 4;
  } else if (blk < 9216) {
    src = Wg; dst = (__bf16*)wgb;
    off = (size_t)(blk - 8192) * 1024 + threadIdx.x * 4;
  } else {
    src = Wo; dst = (__bf16*)wob;
    off = (size_t)(blk - 9216) * 1024 + threadIdx.x * 4;
  }
  float4 f = *(const float4*)(src + off);
  bf16x4v t;
  t[0] = cvt_bf16(f.x); t[1] = cvt_bf16(f.y); t[2] = cvt_bf16(f.z); t[3] = cvt_bf16(f.w);
  *(bf16x4v*)(dst + off) = t;
}

// C = A * Bt^T. A: MxK (bf16 async-staged unless A_FP32); Bt: NxK fp32.
// MODE 2: raw->bf16; 3: sigmoid(acc+bias)->bf16; 4: raw->fp32; 5: sigmoid(acc+bias)->fp32 TRANSPOSED
template <int MODE, bool A_FP32>
__global__ __launch_bounds__(256) void gemm_bt(
    const void* __restrict__ Av, const float* __restrict__ Bt,
    const float* __restrict__ bias, float* __restrict__ Cf, bf16* __restrict__ Cb,
    int M, int N, int K)
{
  __shared__ __align__(16) __bf16 As[128 * 32];
  __shared__ __align__(16) __bf16 Bs[128 * 32];

  const int tid  = threadIdx.x;
  const int lane = tid & 63;
  const int wave = tid >> 6;
  const int tile_m = blockIdx.y * 128;
  const int tile_n = blockIdx.x * 128;
  const int wm = (wave >> 1) * 64;
  const int wn = (wave & 1) * 64;

  const int srow = lane >> 2;
  const int scol = (lane & 3) * 8;

  f32x4 acc[4][4];
#pragma unroll
  for (int i = 0; i < 4; ++i)
#pragma unroll
    for (int j = 0; j < 4; ++j) acc[i][j] = {0.f, 0.f, 0.f, 0.f};

  for (int k0 = 0; k0 < K; k0 += 32) {
    float4 b0[2], b1[2], a0[2], a1[2];
#pragma unroll
    for (int s = 0; s < 2; ++s) {
      int brow = tile_n + s * 64 + wave * 16 + srow;
      if (brow > N - 1) brow = N - 1;
      const float* bp = Bt + (size_t)brow * K + k0 + scol;
      b0[s] = *(const float4*)bp;
      b1[s] = *(const float4*)(bp + 4);
      if (A_FP32) {
        int arow = tile_m + s * 64 + wave * 16 + srow;
        const float* ap = (const float*)Av + (size_t)arow * K + k0 + scol;
        a0[s] = *(const float4*)ap;
        a1[s] = *(const float4*)(ap + 4);
      }
    }
    __syncthreads();
#pragma unroll
    for (int s = 0; s < 2; ++s) {
      if (!A_FP32) {
        int arow = tile_m + s * 64 + wave * 16 + srow;
        async_copy16((const __bf16*)Av + (size_t)arow * K + k0 + scol,
                     &As[(s * 64 + wave * 16 + srow) * 32 + scol]);
      } else {
        bf16x8 ua;
        ua[0] = cvt_bf16(a0[s].x); ua[1] = cvt_bf16(a0[s].y);
        ua[2] = cvt_bf16(a0[s].z); ua[3] = cvt_bf16(a0[s].w);
        ua[4] = cvt_bf16(a1[s].x); ua[5] = cvt_bf16(a1[s].y);
        ua[6] = cvt_bf16(a1[s].z); ua[7] = cvt_bf16(a1[s].w);
        *(bf16x8*)&As[(s * 64 + wave * 16 + srow) * 32 + scol] = ua;
      }
      bf16x8 u;
      u[0] = cvt_bf16(b0[s].x); u[1] = cvt_bf16(b0[s].y);
      u[2] = cvt_bf16(b0[s].z); u[3] = cvt_bf16(b0[s].w);
      u[4] = cvt_bf16(b1[s].x); u[5] = cvt_bf16(b1[s].y);
      u[6] = cvt_bf16(b1[s].z); u[7] = cvt_bf16(b1[s].w);
      *(bf16x8*)&Bs[(s * 64 + wave * 16 + srow) * 32 + scol] = u;
    }
    __syncthreads();

    bf16x8 af[4], bfr[4];
#pragma unroll
    for (int i = 0; i < 4; ++i)
      af[i] = *(const bf16x8*)&As[(wm + i * 16 + (lane & 15)) * 32 + (lane >> 4) * 8];
#pragma unroll
    for (int j = 0; j < 4; ++j)
      bfr[j] = *(const bf16x8*)&Bs[(wn + j * 16 + (lane & 15)) * 32 + (lane >> 4) * 8];

#pragma unroll
    for (int i = 0; i < 4; ++i)
#pragma unroll
      for (int j = 0; j < 4; ++j)
        acc[i][j] = __builtin_amdgcn_mfma_f32_16x16x32_bf16(af[i], bfr[j], acc[i][j], 0, 0, 0);
  }

#pragma unroll
  for (int i = 0; i < 4; ++i) {
#pragma unroll
    for (int j = 0; j < 4; ++j) {
#pragma unroll
      for (int r = 0; r < 4; ++r) {
        int gm = tile_m + wm + i * 16 + (lane >> 4) * 4 + r;
        int gn = tile_n + wn + j * 16 + (lane & 15);
        if (gn < N) {
          float val = acc[i][j][r];
          if (MODE == 3 || MODE == 5) {
            float bv = bias ? bias[gn] : 0.f;
            val = 1.f / (1.f + __expf(-(val + bv)));
          }
          if (MODE == 4)      Cf[(size_t)gm * N + gn] = val;
          else if (MODE == 5) Cf[(size_t)gn * M + gm] = val;
          else                Cb[(size_t)gm * N + gn] = (bf16)val;
        }
      }
    }
  }
}

// Final GEMM with fused LN+gate on the A operand. 64-row tiles -> 512
// blocks = 2 blocks/CU. Per head: stage FULL 64-k B-slab (Bs2[2][128][32])
// -> 2 barriers/head. Head loop software-pipelined. XCD-bijective swizzle.
__global__ __launch_bounds__(256) void gemm_bb_ln(
    const bf16* __restrict__ o, const bf16* __restrict__ g,
    const float* __restrict__ lnw, const float* __restrict__ lnb,
    const bf16* __restrict__ Bw, float* __restrict__ C)
{
  __shared__ __align__(16) __bf16 As2[64][72];        // 9 KB (72-pad)
  __shared__ __align__(16) __bf16 Bs2[2][128][32];    // 16 KB (sub-major)
  __shared__ float sW[64], sB[64];

  const int bx = blockIdx.x;                       // 512 blocks
  const int logical = (bx & 7) * 64 + (bx >> 3);   // bijective XCD swizzle
  const int tile_m = (logical >> 3) * 64;
  const int tile_n = (logical & 7) * 128;

  const int tid  = threadIdx.x;
  const int lane = tid & 63;
  const int wave = tid >> 6;
  const int wm = (wave >> 1) * 32;     // row quadrant 0/32
  const int wn = (wave & 1) * 64;      // col half 0/64
  const int srow = lane >> 2;
  const int scol = (lane & 3) * 8;
  const int rl  = tid >> 2;            // local A row 0..63
  const int qtr = tid & 3;             // column quarter (16 cols each)

  if (tid < 64) { sW[tid] = lnw[tid]; sB[tid] = lnb[tid]; }

  const __bf16* obase = (const __bf16*)o + (size_t)(tile_m + rl) * 1024 + qtr * 16;
  const __bf16* gbase = (const __bf16*)g + (size_t)(tile_m + rl) * 1024 + qtr * 16;

  f32x4 acc[2][4];
#pragma unroll
  for (int i = 0; i < 2; ++i)
#pragma unroll
    for (int j = 0; j < 4; ++j) acc[i][j] = {0.f, 0.f, 0.f, 0.f};

  // preload head 0 (16 cols per thread)
  bf16x8 ov0, ov1, gv0, gv1;
  ov0 = *(const bf16x8*)(obase);
  ov1 = *(const bf16x8*)(obase + 8);
  gv0 = *(const bf16x8*)(gbase);
  gv1 = *(const bf16x8*)(gbase + 8);

  for (int h = 0; h < 16; ++h) {
    // issue NEXT head's o/g loads first (in flight across barriers + MFMA)
    bf16x8 no0, no1, ng0, ng1;
    if (h + 1 < 16) {
      const __bf16* op = obase + (h + 1) * 64;
      const __bf16* gp = gbase + (h + 1) * 64;
      no0 = *(const bf16x8*)(op);
      no1 = *(const bf16x8*)(op + 8);
      ng0 = *(const bf16x8*)(gp);
      ng1 = *(const bf16x8*)(gp + 8);
    }

    __syncthreads();   // prior head's MFMA reads of As2/Bs2 complete

    // issue full 64-k B-slab stage for head h (both subs)
#pragma unroll
    for (int sub = 0; sub < 2; ++sub)
#pragma unroll
      for (int s = 0; s < 2; ++s) {
        int brow = tile_n + s * 64 + wave * 16 + srow;
        async_copy16((const __bf16*)Bw + (size_t)brow * 1024 + h * 64 + sub * 32 + scol,
                     &Bs2[sub][s * 64 + wave * 16 + srow][scol]);
      }

    // ---- LN + gate for head h -> As2 (row rl; 4 threads per row) ----
    float sum = 0.f;
#pragma unroll
    for (int e = 0; e < 8; ++e)
      sum += (float)ov0[e] + (float)ov1[e];
    sum += __shfl_xor(sum, 1);
    sum += __shfl_xor(sum, 2);
    float mu = sum * (1.f / 64.f);
    float vv = 0.f;
#pragma unroll
    for (int e = 0; e < 8; ++e) {
      float d0 = (float)ov0[e] - mu, d1 = (float)ov1[e] - mu;
      vv += d0 * d0 + d1 * d1;
    }
    vv += __shfl_xor(vv, 1);
    vv += __shfl_xor(vv, 2);
    float rstd = rsqrtf(vv * (1.f / 64.f) + 1e-5f);

    bf16x8 res0, res1;
#pragma unroll
    for (int e = 0; e < 8; ++e) {
      int c0 = qtr * 16 + e;
      res0[e] = cvt_bf16((((float)ov0[e] - mu) * rstd * sW[c0] + sB[c0]) * (float)gv0[e]);
      res1[e] = cvt_bf16((((float)ov1[e] - mu) * rstd * sW[c0 + 8] + sB[c0 + 8]) * (float)gv1[e]);
    }
    *(bf16x8*)&As2[rl][qtr * 16 + 0] = res0;
    *(bf16x8*)&As2[rl][qtr * 16 + 8] = res1;

    __syncthreads();               // Bs2 landed + As2 visible

#pragma unroll
    for (int sub = 0; sub < 2; ++sub) {
      bf16x8 af[2], bfr[4];
#pragma unroll
      for (int i = 0; i < 2; ++i)
        af[i] = *(const bf16x8*)&As2[wm + i * 16 + (lane & 15)][(lane >> 4) * 8 + sub * 32];
#pragma unroll
      for (int j = 0; j < 4; ++j)
        bfr[j] = *(const bf16x8*)&Bs2[sub][wn + j * 16 + (lane & 15)][(lane >> 4) * 8];

#pragma unroll
      for (int i = 0; i < 2; ++i)
#pragma unroll
        for (int j = 0; j < 4; ++j)
          acc[i][j] = __builtin_amdgcn_mfma_f32_16x16x32_bf16(af[i], bfr[j], acc[i][j], 0, 0, 0);
    }

    if (h + 1 < 16) {
      ov0 = no0; ov1 = no1;
      gv0 = ng0; gv1 = ng1;
    }
  }

#pragma unroll
  for (int i = 0; i < 2; ++i)
#pragma unroll
    for (int j = 0; j < 4; ++j)
#pragma unroll
      for (int r = 0; r < 4; ++r) {
        int gm = tile_m + wm + i * 16 + (lane >> 4) * 4 + r;
        int gn = tile_n + wn + j * 16 + (lane & 15);
        C[(size_t)gm * 1024 + gn] = acc[i][j][r];
      }
}

// Fused 4-projection + beta GEMM. 1-D grid 1056 blocks:
//  bx < 1024: GEMM tiles; XCD partition = 8m x 16n per XCD
//  (footprint 2MB A + 4MB W = 6MB). bx >= 1024: beta tiles.
__global__ __launch_bounds__(256) void mega_gemm2(
    const bf16* __restrict__ Av, const bf16* __restrict__ W4b,
    const float* __restrict__ Wb, const float* __restrict__ bb,
    const float* __restrict__ ba, bf16* __restrict__ C4,
    float* __restrict__ betab)
{
  __shared__ __align__(16) __bf16 As[128 * 32];
  __shared__ __align__(16) __bf16 Bs[128 * 32];

  const int bx = blockIdx.x;
  const bool isbeta = (bx >= 1024);
  int tile_m, tile_n;
  if (!isbeta) {
    const int xcd = bx & 7;
    const int local = bx >> 3;        // 0..127
    const int mg = xcd >> 1;          // 0..3 (M groups of 8)
    const int ng = xcd & 1;           // 0..1 (N groups of 16)
    const int lm = local & 7;         // 0..7
    const int ln = local >> 3;        // 0..15
    tile_m = (mg * 8 + lm) * 128;
    tile_n = (ng * 16 + ln) * 128;
  } else {
    tile_m = (bx - 1024) * 128;
    tile_n = 0;
  }
  const int grp = tile_n >> 10;
  const int tnl = tile_n & 1023;

  const int tid  = threadIdx.x;
  const int lane = tid & 63;
  const int wave = tid >> 6;
  const int wm = (wave >> 1) * 64;
  const int wn = (wave & 1) * 64;

  const int srow = lane >> 2;
  const int scol = (lane & 3) * 8;

  f32x4 acc[4][4];
#pragma unroll
  for (int i = 0; i < 4; ++i)
#pragma unroll
    for (int j = 0; j < 4; ++j) acc[i][j] = {0.f, 0.f, 0.f, 0.f};

  const __bf16* Wp = (const __bf16*)W4b + (size_t)grp * 1024 * 1024;

  for (int k0 = 0; k0 < 1024; k0 += 32) {
    float4 b0[2], b1[2];
    if (isbeta) {
#pragma unroll
      for (int s = 0; s < 2; ++s) {
        int brow = s * 64 + wave * 16 + srow;
        if (brow > 15) brow = 15;
        const float* bp = Wb + (size_t)brow * 1024 + k0 + scol;
        b0[s] = *(const float4*)bp;
        b1[s] = *(const float4*)(bp + 4);
      }
    }
    __syncthreads();
#pragma unroll
    for (int s = 0; s < 2; ++s) {
      int arow = tile_m + s * 64 + wave * 16 + srow;
      async_copy16((const __bf16*)Av + (size_t)arow * 1024 + k0 + scol,
                   &As[(s * 64 + wave * 16 + srow) * 32 + scol]);
      if (!isbeta) {
        int brow = tnl + s * 64 + wave * 16 + srow;
        async_copy16(Wp + (size_t)brow * 1024 + k0 + scol,
                     &Bs[(s * 64 + wave * 16 + srow) * 32 + scol]);
      } else {
        bf16x8 u;
        u[0] = cvt_bf16(b0[s].x); u[1] = cvt_bf16(b0[s].y);
        u[2] = cvt_bf16(b0[s].z); u[3] = cvt_bf16(b0[s].w);
        u[4] = cvt_bf16(b1[s].x); u[5] = cvt_bf16(b1[s].y);
        u[6] = cvt_bf16(b1[s].z); u[7] = cvt_bf16(b1[s].w);
        *(bf16x8*)&Bs[(s * 64 + wave * 16 + srow) * 32 + scol] = u;
      }
    }
    __syncthreads();

    bf16x8 af[4], bfr[4];
#pragma unroll
    for (int i = 0; i < 4; ++i)
      af[i] = *(const bf16x8*)&As[(wm + i * 16 + (lane & 15)) * 32 + (lane >> 4) * 8];
#pragma unroll
    for (int j = 0; j < 4; ++j)
      bfr[j] = *(const bf16x8*)&Bs[(wn + j * 16 + (lane & 15)) * 32 + (lane >> 4) * 8];

#pragma unroll
    for (int i = 0; i < 4; ++i)
#pragma unroll
      for (int j = 0; j < 4; ++j)
        acc[i][j] = __builtin_amdgcn_mfma_f32_16x16x32_bf16(af[i], bfr[j], acc[i][j], 0, 0, 0);
  }

  if (!isbeta) {
    bf16* Cp = (bf16*)((__bf16*)C4 + (size_t)grp * 4096 * 1024);
#pragma unroll
    for (int i = 0; i < 4; ++i)
#pragma unroll
      for (int j = 0; j < 4; ++j)
#pragma unroll
        for (int r = 0; r < 4; ++r) {
          int gm = tile_m + wm + i * 16 + (lane >> 4) * 4 + r;
          int col = tnl + wn + j * 16 + (lane & 15);
          float val = acc[i][j][r];
          if (grp == 3) val = 1.f / (1.f + __expf(-(val + ba[col])));
          ((__bf16*)Cp)[(size_t)gm * 1024 + col] = cvt_bf16(val);
        }
  } else {
#pragma unroll
    for (int i = 0; i < 4; ++i)
#pragma unroll
      for (int j = 0; j < 4; ++j)
#pragma unroll
        for (int r = 0; r < 4; ++r) {
          int gm = tile_m + wm + i * 16 + (lane >> 4) * 4 + r;
          int gn = wn + j * 16 + (lane & 15);
          if (gn < 16) {
            float val = 1.f / (1.f + __expf(-(acc[i][j][r] + bb[gn])));
            betab[(size_t)gn * 4096 + gm] = val;
          }
        }
  }
}

// shared conv body: causal depthwise K=4 + bias + SiLU (+scale), x8 vec.
__device__ __forceinline__ void conv_body(
    int idx, const bf16* __restrict__ z, const float* __restrict__ w,
    const float* __restrict__ bias, bf16* __restrict__ out, float scale)
{
  int c8 = idx & 127;
  int m  = idx >> 7;
  int t  = m & 2047;
  int c0 = c8 * 8;

  const __bf16* base = (const __bf16*)z + (size_t)m * 1024 + c0;
  const bf16x8 zzero = __builtin_bit_cast(bf16x8, (u32x4){0u, 0u, 0u, 0u});
  bf16x8 z3 = *(const bf16x8*)base;
  bf16x8 z2 = (t >= 1) ? *(const bf16x8*)(base - 1024) : zzero;
  bf16x8 z1 = (t >= 2) ? *(const bf16x8*)(base - 2048) : zzero;
  bf16x8 z0 = (t >= 3) ? *(const bf16x8*)(base - 3072) : zzero;

  const float* wp = w + c0 * 4;
  bf16x8 res;
#pragma unroll
  for (int e = 0; e < 8; ++e) {
    float4 we = *(const float4*)(wp + e * 4);
    float acc = bias[c0 + e] + (float)z3[e] * we.w;
    acc += (float)z2[e] * we.z;
    acc += (float)z1[e] * we.y;
    acc += (float)z0[e] * we.x;
    float s = acc / (1.f + __expf(-acc));
    res[e] = cvt_bf16(s * scale);
  }
  *(bf16x8*)((__bf16*)out + (size_t)m * 1024 + c0) = res;
}

// standalone conv (fallback path)
__global__ __launch_bounds__(256) void conv_silu_kernel(
    const bf16* __restrict__ z, const float* __restrict__ w,
    const float* __restrict__ bias, bf16* __restrict__ out, float scale)
{
  conv_body(blockIdx.x * 256 + threadIdx.x, z, w, bias, out, scale);
}

// conv_q + conv_k in one launch (disjoint planes). Grid 4096.
__global__ __launch_bounds__(256) void conv2_kernel(
    const bf16* __restrict__ zq, const bf16* __restrict__ zk,
    const float* __restrict__ qcw, const float* __restrict__ qcb,
    const float* __restrict__ kcw, const float* __restrict__ kcb,
    bf16* __restrict__ oq, bf16* __restrict__ ok)
{
  int sec = blockIdx.x >> 11;
  int bx  = blockIdx.x & 2047;
  int idx = bx * 256 + threadIdx.x;
  if (sec == 0) conv_body(idx, zq, qcw, qcb, oq, 1.f);
  else          conv_body(idx, zk, kcw, kcb, ok, 0.125f);
}

// conv_v + kk in one launch (kk reads k from PREVIOUS launch). Grid 3072.
__global__ __launch_bounds__(256) void convv_kk_kernel(
    const bf16* __restrict__ zv, const float* __restrict__ vcw,
    const float* __restrict__ vcb, bf16* __restrict__ ov,
    const bf16* __restrict__ k, const float* __restrict__ betab,
    float* __restrict__ G)
{
  if (blockIdx.x < 2048) {
    conv_body(blockIdx.x * 256 + threadIdx.x, zv, vcw, vcb, ov, 1.f);
    return;
  }
  int gtid = (blockIdx.x - 2048) * 256 + threadIdx.x;
  int out = gtid >> 2;           // h*4096 + m
  int j   = gtid & 3;
  int h = out >> 12;
  int m = out & 4095;
  int t = m & 2047;
  float s = 0.f;
  if (t > 0) {
    const __bf16* r1 = (const __bf16*)k + (size_t)m * 1024 + h * 64 + j * 16;
    const __bf16* r0 = r1 - 1024;
    bf16x8 a0 = *(const bf16x8*)r0;
    bf16x8 a1 = *(const bf16x8*)(r0 + 8);
    bf16x8 b0 = *(const bf16x8*)r1;
    bf16x8 b1 = *(const bf16x8*)(r1 + 8);
#pragma unroll
    for (int e = 0; e < 8; ++e)
      s += (float)a0[e] * (float)b0[e] + (float)a1[e] * (float)b1[e];
  }
  s += __shfl_xor(s, 1);
  s += __shfl_xor(s, 2);
  if (j == 0) G[out] = betab[out] * s;
}

// kk standalone (fallback)
__global__ __launch_bounds__(256) void kk_kernel(
    const bf16* __restrict__ k, const float* __restrict__ betab,
    float* __restrict__ G)
{
  int tid = blockIdx.x * 256 + threadIdx.x;
  int out = tid >> 2;
  int j   = tid & 3;
  int h = out >> 12;
  int m = out & 4095;
  int t = m & 2047;
  float s = 0.f;
  if (t > 0) {
    const __bf16* r1 = (const __bf16*)k + (size_t)m * 1024 + h * 64 + j * 16;
    const __bf16* r0 = r1 - 1024;
    bf16x8 a0 = *(const bf16x8*)r0;
    bf16x8 a1 = *(const bf16x8*)(r0 + 8);
    bf16x8 b0 = *(const bf16x8*)r1;
    bf16x8 b1 = *(const bf16x8*)(r1 + 8);
#pragma unroll
    for (int e = 0; e < 8; ++e)
      s += (float)a0[e] * (float)b0[e] + (float)a1[e] * (float)b1[e];
  }
  s += __shfl_xor(s, 1);
  s += __shfl_xor(s, 2);
  if (j == 0) G[out] = betab[out] * s;
}

// One scan step (constant word indices only).
#define SCAN_STEP(i, KN0, KN1, Q0, Q1, WV, WA, BT, GT, LAST)                  \
  {                                                                           \
    const float vr = ((i) & 1) ? bcf((WV) & 0xffff0000u) : bcf((WV) << 16);   \
    const float ar = ((i) & 1) ? bcf((WA) & 0xffff0000u) : bcf((WA) << 16);   \
    float unxt = 0.f;                                                         \
    f32x2 k2n0 = {0.f, 0.f}, k2n1 = {0.f, 0.f};                               \
    if (!(LAST)) {                                                            \
      k2n0 = unpk(KN0); k2n1 = unpk(KN1);                                     \
      f32x2 dd = S20 * k2n0; dd += S21 * k2n1;                                \
      unxt = dd[0] + dd[1];                                                   \
      unxt += dpp_f<0xB1>(unxt);  unxt += dpp_f<0x4E>(unxt);                  \
      unxt += dpp_f<0x141>(unxt); unxt += dpp_f<0x140>(unxt);                 \
    } else { Sold0 = S20; Sold1 = S21; }                                      \
    float A_ = (BT) * __builtin_fmaf(aprev, u, -vr);                          \
    cc = __builtin_fmaf(-cc, (GT), A_);                                       \
    f32x2 q20 = unpk(Q0), q21 = unpk(Q1);                                     \
    const f32x2 cc2 = {cc, cc}, arv = {ar, ar};                               \
    f32x2 oo;                                                                 \
    { f32x2 t0 = cc2 * k2c0; S20 = arv * S20 - t0; oo = S20 * q20;            \
      f32x2 t1 = cc2 * k2c1; S21 = arv * S21 - t1; oo += S21 * q21; }         \
    so[(i)][lane] = oo[0] + oo[1];                                            \
    aprev = ar;                                                               \
    if (!(LAST)) { k2c0 = k2n0; k2c1 = k2n1; u = unxt; }                      \
  }

// Load one 2-step group (g = 0..7) into a named set (14 regs).
#define LOADG(KS, QS, VS, AS, BS, GS, g)                                      \
  KS = *(const u32x4*)&skT[buf][sg][(g) * 8];                                 \
  QS = *(const u32x4*)&sqT[buf][sg][(g) * 8];                                 \
  VS = *(const unsigned int*)&svaT[buf][0][r4][(g) * 2];                      \
  AS = *(const unsigned int*)&svaT[buf][1][r4][(g) * 2];                      \
  BS = *(const f32x2*)&sbeta[c * 16 + (g) * 2];                               \
  GS = *(const f32x2*)&sG[c * 16 + (g) * 2];

// FUSED kernel: blocks 0..511 = delta-rule scan (single wave; threads>=64
// exit; NO barriers; s_setprio(1)). Blocks 512..767 = g-GEMM.
__global__ __launch_bounds__(256) void scan_gemm_kernel(
    const bf16* __restrict__ q, const bf16* __restrict__ k,
    const bf16* __restrict__ v, const bf16* __restrict__ a,
    const float* __restrict__ betab, const float* __restrict__ gkk,
    bf16* __restrict__ o,
    const float* __restrict__ x, const bf16* __restrict__ Wgb,
    bf16* __restrict__ gout)
{
  __shared__ __align__(16) __bf16 skT[2][16][72];
  __shared__ __align__(16) __bf16 sqT[2][16][72];
  __shared__ __align__(16) __bf16 svaT[2][2][4][16];
  __shared__ __align__(16) float  so[16][68];
  __shared__ __align__(16) __bf16 so2[16][4];
  __shared__ float sbeta[2048];
  __shared__ float sG[2048];
  __shared__ __align__(16) __bf16 As[128 * 32];
  __shared__ __align__(16) __bf16 Bs[128 * 32];

  if (blockIdx.x >= 512) {
    const int gb   = blockIdx.x - 512;
    const int tid  = threadIdx.x;
    const int lane = tid & 63;
    const int wave = tid >> 6;
    const int tile_m = (gb >> 3) * 128;
    const int tile_n = (gb & 7) * 128;
    const int wm = (wave >> 1) * 64;
    const int wn = (wave & 1) * 64;
    const int srow = lane >> 2;
    const int scol = (lane & 3) * 8;

    f32x4 acc[4][4];
#pragma unroll
    for (int i = 0; i < 4; ++i)
#pragma unroll
      for (int j = 0; j < 4; ++j) acc[i][j] = {0.f, 0.f, 0.f, 0.f};

    for (int k0 = 0; k0 < 1024; k0 += 32) {
      float4 a0[2], a1[2];
#pragma unroll
      for (int s = 0; s < 2; ++s) {
        int arow = tile_m + s * 64 + wave * 16 + srow;
        const float* ap = x + (size_t)arow * 1024 + k0 + scol;
        a0[s] = *(const float4*)ap;
        a1[s] = *(const float4*)(ap + 4);
      }
      __syncthreads();
#pragma unroll
      for (int s = 0; s < 2; ++s) {
        bf16x8 ua;
        ua[0] = cvt_bf16(a0[s].x); ua[1] = cvt_bf16(a0[s].y);
        ua[2] = cvt_bf16(a0[s].z); ua[3] = cvt_bf16(a0[s].w);
        ua[4] = cvt_bf16(a1[s].x); ua[5] = cvt_bf16(a1[s].y);
        ua[6] = cvt_bf16(a1[s].z); ua[7] = cvt_bf16(a1[s].w);
        *(bf16x8*)&As[(s * 64 + wave * 16 + srow) * 32 + scol] = ua;
        int brow = tile_n + s * 64 + wave * 16 + srow;
        async_copy16((const __bf16*)Wgb + (size_t)brow * 1024 + k0 + scol,
                     &Bs[(s * 64 + wave * 16 + srow) * 32 + scol]);
      }
      __syncthreads();

      bf16x8 af[4], bfr[4];
#pragma unroll
      for (int i = 0; i < 4; ++i)
        af[i] = *(const bf16x8*)&As[(wm + i * 16 + (lane & 15)) * 32 + (lane >> 4) * 8];
#pragma unroll
      for (int j = 0; j < 4; ++j)
        bfr[j] = *(const bf16x8*)&Bs[(wn + j * 16 + (lane & 15)) * 32 + (lane >> 4) * 8];

#pragma unroll
      for (int i = 0; i < 4; ++i)
#pragma unroll
        for (int j = 0; j < 4; ++j)
          acc[i][j] = __builtin_amdgcn_mfma_f32_16x16x32_bf16(af[i], bfr[j], acc[i][j], 0, 0, 0);
    }

#pragma unroll
    for (int i = 0; i < 4; ++i)
#pragma unroll
      for (int j = 0; j < 4; ++j)
#pragma unroll
        for (int r = 0; r < 4; ++r) {
          int gm = tile_m + wm + i * 16 + (lane >> 4) * 4 + r;
          int gn = tile_n + wn + j * 16 + (lane & 15);
          float val = 1.f / (1.f + __expf(-acc[i][j][r]));
          gout[(size_t)gm * 1024 + gn] = (bf16)val;
        }
    return;
  }

  // ---------------- scan path (single wave; extra waves exit) ----------------
  if (threadIdx.x >= 64) return;
  __builtin_amdgcn_s_setprio(1);

  const int blk = blockIdx.x;
  const int qd = blk >> 5;
  const int bh = blk & 31;
  const int b = bh >> 4, h = bh & 15;
  const int lane = threadIdx.x;
  const int r4 = lane >> 4;
  const int sg = lane & 15;

  {
    const float* bp = betab + (size_t)h * 4096 + b * 2048;
    const float* gp = gkk   + (size_t)h * 4096 + b * 2048;
    for (int t4 = lane * 4; t4 < 2048; t4 += 256) {
      *(float4*)&sbeta[t4] = *(const float4*)(bp + t4);
      *(float4*)&sG[t4]    = *(const float4*)(gp + t4);
    }
  }

  const size_t bkq = (size_t)b * 2048 * 1024 + h * 64;
  const size_t bva = bkq + qd * 4;
  const __bf16* kp = (const __bf16*)k;
  const __bf16* qp = (const __bf16*)q;

  const int g_st = lane >> 3;
  const int g_cg = (lane & 7) * 8;
  const int sgp  = (lane & 7) * 2;
  const int va_vh = (lane >> 4) & 1;
  const int va_st = lane & 15;

  bf16x8 pk0, pk1, pq0, pq1;
  bf16x4v pva;
  auto fetch = [&](int t0) {
    int st0 = t0 + g_st, st1 = t0 + 8 + g_st;
    pk0 = *(const bf16x8*)(kp + bkq + (size_t)st0 * 1024 + g_cg);
    pk1 = *(const bf16x8*)(kp + bkq + (size_t)st1 * 1024 + g_cg);
    pq0 = *(const bf16x8*)(qp + bkq + (size_t)st0 * 1024 + g_cg);
    pq1 = *(const bf16x8*)(qp + bkq + (size_t)st1 * 1024 + g_cg);
    if (lane < 32) {
      const __bf16* src = va_vh ? (const __bf16*)a : (const __bf16*)v;
      pva = *(const bf16x4v*)(src + bva + (size_t)(t0 + va_st) * 1024);
    }
  };
  auto commit = [&](int cb) {
    {
      u32x4 wk = __builtin_bit_cast(u32x4, pk0);
      u32x4 wq = __builtin_bit_cast(u32x4, pq0);
      u32x2 lo, hi;
      lo[0] = wk[0]; lo[1] = wk[1]; hi[0] = wk[2]; hi[1] = wk[3];
      *(u32x2*)&skT[cb][sgp][g_st * 4]     = lo;
      *(u32x2*)&skT[cb][sgp + 1][g_st * 4] = hi;
      lo[0] = wq[0]; lo[1] = wq[1]; hi[0] = wq[2]; hi[1] = wq[3];
      *(u32x2*)&sqT[cb][sgp][g_st * 4]     = lo;
      *(u32x2*)&sqT[cb][sgp + 1][g_st * 4] = hi;
    }
    {
      u32x4 wk = __builtin_bit_cast(u32x4, pk1);
      u32x4 wq = __builtin_bit_cast(u32x4, pq1);
      u32x2 lo, hi;
      lo[0] = wk[0]; lo[1] = wk[1]; hi[0] = wk[2]; hi[1] = wk[3];
      *(u32x2*)&skT[cb][sgp][(8 + g_st) * 4]     = lo;
      *(u32x2*)&skT[cb][sgp + 1][(8 + g_st) * 4] = hi;
      lo[0] = wq[0]; lo[1] = wq[1]; hi[0] = wq[2]; hi[1] = wq[3];
      *(u32x2*)&sqT[cb][sgp][(8 + g_st) * 4]     = lo;
      *(u32x2*)&sqT[cb][sgp + 1][(8 + g_st) * 4] = hi;
    }
    if (lane < 32) {
#pragma unroll
      for (int r = 0; r < 4; ++r) svaT[cb][va_vh][r][va_st] = pva[r];
    }
  };

  fetch(0); commit(0);

  f32x2 S20 = {0.f, 0.f}, S21 = {0.f, 0.f};
  f32x2 Sold0 = {0.f, 0.f}, Sold1 = {0.f, 0.f};
  float u = 0.f, cc = 0.f, aprev = 0.f;

  auto unpk = [&](unsigned int w) -> f32x2 {
    f32x2 r; r[0] = bcf(w << 16); r[1] = bcf(w & 0xffff0000u); return r;
  };

  for (int c = 0; c < 128; ++c) {
    const int buf = c & 1;
    const bool hasNext = (c + 1 < 128);

    if (hasNext) fetch((c + 1) * 16);

    u32x4 kA, qA, kB, qB, kC, qC;
    unsigned int vA, aA, vB, aB, vC, aC;
    f32x2 bA, gA, bB, gB, bC, gC;

    LOADG(kA, qA, vA, aA, bA, gA, 0)
    LOADG(kB, qB, vB, aB, bB, gB, 1)
    LOADG(kC, qC, vC, aC, bC, gC, 2)

    f32x2 k2c0 = unpk(kA[0]);
    f32x2 k2c1 = unpk(kA[1]);
    {
      f32x2 dd = Sold0 * k2c0;
      dd += Sold1 * k2c1;
      float un = dd[0] + dd[1];
      un += dpp_f<0xB1>(un);
      un += dpp_f<0x4E>(un);
      un += dpp_f<0x141>(un);
      un += dpp_f<0x140>(un);
      u = un;
    }

    SCAN_STEP(0,  kA[2], kA[3], qA[0], qA[1], vA, aA, bA[0], gA[0], false)
    SCAN_STEP(1,  kB[0], kB[1], qA[2], qA[3], vA, aA, bA[1], gA[1], false)
    LOADG(kA, qA, vA, aA, bA, gA, 3)
    SCAN_STEP(2,  kB[2], kB[3], qB[0], qB[1], vB, aB, bB[0], gB[0], false)
    SCAN_STEP(3,  kC[0], kC[1], qB[2], qB[3], vB, aB, bB[1], gB[1], false)
    LOADG(kB, qB, vB, aB, bB, gB, 4)
    SCAN_STEP(4,  kC[2], kC[3], qC[0], qC[1], vC, aC, bC[0], gC[0], false)
    SCAN_STEP(5,  kA[0], kA[1], qC[2], qC[3], vC, aC, bC[1], gC[1], false)
    LOADG(kC, qC, vC, aC, bC, gC, 5)
    SCAN_STEP(6,  kA[2], kA[3], qA[0], qA[1], vA, aA, bA[0], gA[0], false)
    SCAN_STEP(7,  kB[0], kB[1], qA[2], qA[3], vA, aA, bA[1], gA[1], false)
    LOADG(kA, qA, vA, aA, bA, gA, 6)
    SCAN_STEP(8,  kB[2], kB[3], qB[0], qB[1], vB, aB, bB[0], gB[0], false)
    SCAN_STEP(9,  kC[0], kC[1], qB[2], qB[3], vB, aB, bB[1], gB[1], false)
    LOADG(kB, qB, vB, aB, bB, gB, 7)
    SCAN_STEP(10, kC[2], kC[3], qC[0], qC[1], vC, aC, bC[0], gC[0], false)
    SCAN_STEP(11, kA[0], kA[1], qC[2], qC[3], vC, aC, bC[1], gC[1], false)
    SCAN_STEP(12, kA[2], kA[3], qA[0], qA[1], vA, aA, bA[0], gA[0], false)
    SCAN_STEP(13, kB[0], kB[1], qA[2], qA[3], vA, aA, bA[1], gA[1], false)
    SCAN_STEP(14, kB[2], kB[3], qB[0], qB[1], vB, aB, bB[0], gB[0], false)
    SCAN_STEP(15, kB[2], kB[3], qB[2], qB[3], vB, aB, bB[1], gB[1], true)

    {
      int st = lane >> 2, rr = lane & 3;
      float4 A0 = *(const float4*)&so[st][rr * 16];
      float4 A1 = *(const float4*)&so[st][rr * 16 + 4];
      float4 A2 = *(const float4*)&so[st][rr * 16 + 8];
      float4 A3 = *(const float4*)&so[st][rr * 16 + 12];
      float s = (((A0.x + A0.y) + (A0.z + A0.w)) + ((A1.x + A1.y) + (A1.z + A1.w)))
              + (((A2.x + A2.y) + (A2.z + A2.w)) + ((A3.x + A3.y) + (A3.z + A3.w)));
      so2[st][rr] = cvt_bf16(s);
    }
    if (lane < 16)
      *(bf16x4v*)((__bf16*)o + bva + (size_t)(c * 16 + lane) * 1024) =
          *(const bf16x4v*)&so2[lane][0];

    if (hasNext) commit(buf ^ 1);
  }
}

// LayerNorm over DV=64 per (b,t,h) row, *ln_w+ln_b, *gate -> bf16 (fallback)
__global__ __launch_bounds__(256) void ln_gate_kernel(
    const bf16* __restrict__ o, const bf16* __restrict__ g,
    const float* __restrict__ lnw, const float* __restrict__ lnb,
    bf16* __restrict__ out)
{
  int row = blockIdx.x * 4 + (threadIdx.x >> 6);
  int lane = threadIdx.x & 63;
  size_t idx = (size_t)row * 64 + lane;
  float xv = (float)o[idx];
  float mu = xv;
#pragma unroll
  for (int s = 1; s < 64; s <<= 1) mu += __shfl_xor(mu, s);
  mu *= (1.f / 64.f);
  float d = xv - mu;
  float vv = d * d;
#pragma unroll
  for (int s = 1; s < 64; s <<= 1) vv += __shfl_xor(vv, s);
  vv *= (1.f / 64.f);
  float y = d * rsqrtf(vv + 1e-5f) * lnw[lane] + lnb[lane];
  y *= (float)g[idx];
  out[idx] = (bf16)y;
}

extern "C" void kernel_launch(void* const* d_in, const int* in_sizes, int n_in,
                              void* d_out, int out_size, void* d_ws, size_t ws_size,
                              hipStream_t stream)
{
  const float* x   = (const float*)d_in[0];
  const float* Wq  = (const float*)d_in[1];
  const float* Wk  = (const float*)d_in[2];
  const float* Wv  = (const float*)d_in[3];
  const float* Wa  = (const float*)d_in[4];
  const float* ba  = (const float*)d_in[5];
  const float* Wb  = (const float*)d_in[6];
  const float* bb  = (const float*)d_in[7];
  const float* Wg  = (const float*)d_in[8];
  const float* Wo  = (const float*)d_in[9];
  const float* qcw = (const float*)d_in[10];
  const float* qcb = (const float*)d_in[11];
  const float* kcw = (const float*)d_in[12];
  const float* kcb = (const float*)d_in[13];
  const float* vcw = (const float*)d_in[14];
  const float* vcb = (const float*)d_in[15];
  const float* lnw = (const float*)d_in[16];
  const float* lnb = (const float*)d_in[17];

  const int M = 4096, HID = 1024;
  const size_t PLANE = (size_t)M * HID;
  const size_t PB = PLANE * sizeof(bf16);          // 8 MB bf16 plane

  char* ws = (char*)d_ws;
  float* outf = (float*)d_out;
  const bool rich = (ws_size >= 5 * PB + 1024);

  dim3 blk(256);
  dim3 g8(8, 32);
  int nconv = (int)((size_t)M * 128 / 256);

  if (rich) {
    bf16* P0 = (bf16*)(ws);
    bf16* P1 = (bf16*)(ws + PB);
    bf16* P2 = (bf16*)(ws + 2 * PB);
    bf16* P3 = (bf16*)(ws + 3 * PB);
    bf16* P4 = (bf16*)(ws + 4 * PB);
    bf16*  xb    = (bf16*)d_out;                            // [0,8M)
    bf16*  W4b   = (bf16*)((char*)d_out + 8 * 1024 * 1024); // [8M,16M)
    bf16*  Kb    = xb;                                      // k-plane
    bf16*  Qb    = W4b;                                     // q-plane
    float* betab = (float*)P4;
    float* gkk   = (float*)((char*)P4 + 256 * 1024);
    bf16*  Wgb   = (bf16*)((char*)P4 + 1024 * 1024);
    bf16*  Wob   = (bf16*)((char*)P4 + 3 * 1024 * 1024);

    // 1. convert x + 6 weight matrices to bf16
    cvtw_kernel<<<10240, blk, 0, stream>>>(x, Wq, Wk, Wv, Wa, Wg, Wo,
                                           xb, W4b, Wgb, Wob);
    // 2. fused 4-projection + beta GEMM (1-D grid, 8m x 16n per-XCD partition)
    mega_gemm2<<<1056, blk, 0, stream>>>(xb, W4b, Wb, bb, ba, P0, betab);
    // 3. conv q (P0->Qb) + conv k (P1->Kb) -- disjoint planes
    conv2_kernel<<<4096, blk, 0, stream>>>(P0, P1, qcw, qcb, kcw, kcb, Qb, Kb);
    // 4. conv v (P2->P1) + kk (reads Kb from launch 3)
    convv_kk_kernel<<<3072, blk, 0, stream>>>(P2, vcw, vcb, P1, Kb, betab, gkk);
    // 5. FUSED scan (o->P0) + g-GEMM (sigmoid(x@Wgb^T)->P2)
    scan_gemm_kernel<<<768, blk, 0, stream>>>(Qb, Kb, P1, P3, betab, gkk, P0,
                                              x, Wgb, P2);
    // 6. final GEMM with fused LN+gate (512 blocks = 2/CU, XCD swizzle,
    //    full-64k B staging: 2 barriers/head)
    gemm_bb_ln<<<512, blk, 0, stream>>>(P0, P2, lnw, lnb, Wob, outf);
  } else {
    bf16* P  = (bf16*)(ws);
    bf16* qb = (bf16*)(ws + PB);
    bf16* kb = (bf16*)(ws + 2 * PB);
    bf16* vb = (bf16*)(ws + 3 * PB);
    float* betab = (float*)d_out;
    float* gkk   = (float*)((char*)d_out + 256 * 1024);
    bf16*  ob    = (bf16*)((char*)d_out + 8 * 1024 * 1024);

    gemm_bt<2, true><<<g8, blk, 0, stream>>>(x, Wq, nullptr, nullptr, P, M, HID, HID);
    conv_silu_kernel<<<nconv, blk, 0, stream>>>(P, qcw, qcb, qb, 1.f);
    gemm_bt<2, true><<<g8, blk, 0, stream>>>(x, Wk, nullptr, nullptr, P, M, HID, HID);
    conv_silu_kernel<<<nconv, blk, 0, stream>>>(P, kcw, kcb, kb, 0.125f);
    gemm_bt<2, true><<<g8, blk, 0, stream>>>(x, Wv, nullptr, nullptr, P, M, HID, HID);
    conv_silu_kernel<<<nconv, blk, 0, stream>>>(P, vcw, vcb, vb, 1.f);
    gemm_bt<3, true><<<g8, blk, 0, stream>>>(x, Wa, ba, nullptr, P, M, HID, HID);
    gemm_bt<5, true><<<dim3(1, 32), blk, 0, stream>>>(x, Wb, bb, betab, nullptr, M, 16, HID);
    kk_kernel<<<1024, blk, 0, stream>>>(kb, betab, gkk);
    scan_gemm_kernel<<<512, blk, 0, stream>>>(qb, kb, vb, P, betab, gkk, ob,
                                              x, nullptr, nullptr);
    gemm_bt<3, true><<<g8, blk, 0, stream>>>(x, Wg, nullptr, nullptr, qb, M, HID, HID);
    ln_gate_kernel<<<M * 16 / 4, blk, 0, stream>>>(ob, qb, lnw, lnb, kb);
    gemm_bt<4, false><<<g8, blk, 0, stream>>>(kb, Wo, nullptr, outf, nullptr, M, HID, HID);
  }
}